// Round 5
// baseline (398.779 us; speedup 1.0000x reference)
//
#include <hip/hip_runtime.h>

#define NTOK 49
#define DIM 192
#define HEADS 6

typedef __bf16 bf16x8 __attribute__((ext_vector_type(8)));
typedef float f32x4 __attribute__((ext_vector_type(4)));
typedef unsigned int u32x2 __attribute__((ext_vector_type(2)));
typedef short s16x4 __attribute__((ext_vector_type(4)));

// ws layout (bytes):
//   [0, 221184)        qkv_w bf16 frag-line layout (576 rows x 192, OT=36), x32-A frags; q rows pre-scaled
//   [221184, 294912)   proj_w bf16 x16-B frag lines: line (ks*12+ot)*512B, lane(q,c): W[ot*16+c][ks*16+q*4+j]
//   [294912, 393216)   bias_cd fp32 [6][16][64][4] in S^T C/D per-lane order
#define WPROJ_USH 110592
#define BIAS_BYTE 294912

#define SCALE 0.17677669529663687f   // 1/sqrt(32)

// O parking: window w's O in d_out slice bytes [w*37632, w*37632+24576) as 48
// x16-A frag lines of 512B: line (ks*4+mt), lane 8B = O[tok mt*16+c][d ks*16+q*4+j] bf16.
#define OUT_WIN_BYTES 37632          // 49*192*4

__device__ __forceinline__ unsigned int pack2(float a, float b) {
    unsigned short lo = __builtin_bit_cast(unsigned short, (__bf16)a);
    unsigned short hi = __builtin_bit_cast(unsigned short, (__bf16)b);
    return (unsigned int)lo | ((unsigned int)hi << 16);
}

__device__ __forceinline__ f32x4 mfma32(int4 a, int4 b, f32x4 c) {
    return __builtin_amdgcn_mfma_f32_16x16x32_bf16(
        __builtin_bit_cast(bf16x8, a), __builtin_bit_cast(bf16x8, b), c, 0, 0, 0);
}

// 16x16x16 bf16 MFMA: A/B layout == x32 C/D layout (4 elems/lane) -> chains
// C/D of one MFMA directly into A/B of the next with NO LDS transpose.
// r4 lesson: raw inline-asm MFMA gets NO compiler hazard s_nops -> sporadic
// stale-register corruption. Use the builtin (compiler models hazards).
#if __has_builtin(__builtin_amdgcn_mfma_f32_16x16x16bf16_1k)
__device__ __forceinline__ f32x4 mfma16(u32x2 a, u32x2 b, f32x4 c) {
    return __builtin_amdgcn_mfma_f32_16x16x16bf16_1k(
        __builtin_bit_cast(s16x4, a), __builtin_bit_cast(s16x4, b), c, 0, 0, 0);
}
#else
__device__ __forceinline__ f32x4 mfma16(u32x2 a, u32x2 b, f32x4 c) {
    f32x4 d;
    // conservative manual hazard padding: srcs settle before, dst settles after
    asm volatile("s_nop 1\n\t"
                 "v_mfma_f32_16x16x16_bf16 %0, %1, %2, %3\n\t"
                 "s_nop 7\n\t"
                 "s_nop 7"
                 : "=v"(d) : "v"(a), "v"(b), "0"(c));
    return d;
}
#endif

// ---------- pre-kernel: weights + bias ----------
__global__ void prep(const float* __restrict__ qkv_w, const float* __restrict__ proj_w,
                     const float* __restrict__ bias_table, const int* __restrict__ rel_index,
                     unsigned short* __restrict__ w16, float* __restrict__ bias_cd) {
    int bid = blockIdx.x;
    if (bid < 72) {
        int c = bid * 256 + threadIdx.x;      // 16B chunk id, 0..18431
        if (c < 13824) {
            // qkv_w: x32 frag lines (unchanged)
            int lane = c & 63;
            int t = c >> 6;
            int ot = t % 36, ks = t / 36;
            int f  = ot * 16 + (lane & 15);
            int k0 = ks * 32 + (lane >> 4) * 8;
            float sc = (f < 192) ? SCALE : 1.0f;   // fold softmax scale into q weights
            const float* p = qkv_w + (size_t)f * DIM + k0;
            float4 a = *(const float4*)p;
            float4 b = *(const float4*)(p + 4);
            uint4 o;
            o.x = pack2(a.x * sc, a.y * sc); o.y = pack2(a.z * sc, a.w * sc);
            o.z = pack2(b.x * sc, b.y * sc); o.w = pack2(b.z * sc, b.w * sc);
            *(uint4*)(w16 + (size_t)c * 8) = o;
        } else {
            // proj_w: x16-B frag lines. line = ks*12+ot (512B); lane(q,c):
            // 4 bf16 = proj_w[ot*16+c][ks*16+q*4 .. +3]
            int cc = c - 13824;                // 0..4607
            int line = cc >> 5;                // 0..143
            int pair = cc & 31;                // covers lanes 2*pair, 2*pair+1
            int ks = line / 12, ot = line % 12;
            unsigned int w[4];
            #pragma unroll
            for (int s = 0; s < 2; ++s) {
                int lane = pair * 2 + s;
                int q = lane >> 4, ci = lane & 15;
                const float* p = proj_w + (size_t)(ot*16 + ci) * DIM + ks*16 + q*4;
                float4 a = *(const float4*)p;
                w[s*2 + 0] = pack2(a.x, a.y);
                w[s*2 + 1] = pack2(a.z, a.w);
            }
            uint4 o = {w[0], w[1], w[2], w[3]};
            *(uint4*)(w16 + WPROJ_USH + (size_t)cc * 8) = o;
        }
    } else {
        int gid = (bid - 72) * 256 + threadIdx.x;     // 0..6143
        int lane = gid & 63;
        int tile = (gid >> 6) & 15;
        int h    = gid >> 10;
        int kt = tile >> 2, qt = tile & 3;            // S^T tile: m=key tile kt, n=qtok tile qt
        int qtok = qt * 16 + (lane & 15);
        int key0 = kt * 16 + (lane >> 4) * 4;
        float4 v;
        float* vp = (float*)&v;
        for (int r = 0; r < 4; ++r) {
            int key = key0 + r;
            float val;
            if (key >= NTOK)       val = -1e30f;      // padded key row -> softmax 0
            else if (qtok >= NTOK) val = 0.0f;        // padded query col: don't care
            else                   val = bias_table[rel_index[qtok * NTOK + key] * HEADS + h];
            vp[r] = val;
        }
        *(float4*)(bias_cd + (size_t)gid * 4) = v;
    }
}

// ---------- K1: attention. 1 block/window, 3 waves, 2 heads per wave ----------
// LDS 24 KB = xs only. ONE barrier; NO LDS scratch: all layout chaining is
// register-to-register via x32->x16 MFMA layout identity.
#define K1_LDS 24576

__global__ __launch_bounds__(192, 2) void win_attn(
    const float* __restrict__ x,
    const float* __restrict__ qkv_b,
    const unsigned short* __restrict__ wq16,
    const float* __restrict__ bias_cd,
    float* __restrict__ outO)
{
    extern __shared__ char smem[];
    const int tid  = threadIdx.x;
    const int lane = tid & 63;
    const int wv   = tid >> 6;                 // wave in block: 0..2
    const int widx = blockIdx.x;               // window
    const int l15  = lane & 15;
    const int quad = lane >> 4;

    // ---- stage x -> xs (bf16 frag-line layout, rows >=49 zero) ----
    #pragma unroll
    for (int i = 0; i < 8; ++i) {
        int c  = tid + i * 192;         // 1536 chunks = (ks*4+mt)*64 + cl
        int cl = c & 63;
        int mt = (c >> 6) & 3;
        int ks = c >> 8;
        int tok = mt * 16 + (cl & 15);
        int d0  = ks * 32 + (cl >> 4) * 8;
        uint4 o = {0u, 0u, 0u, 0u};
        if (tok < NTOK) {
            const float* p = x + ((size_t)widx * NTOK + tok) * DIM + d0;
            float4 a  = *(const float4*)p;
            float4 bb = *(const float4*)(p + 4);
            o.x = pack2(a.x, a.y); o.y = pack2(a.z, a.w);
            o.z = pack2(bb.x, bb.y); o.w = pack2(bb.z, bb.w);
        }
        *(uint4*)(smem + (size_t)c * 16) = o;
    }
    __syncthreads();                   // the ONLY barrier

    char* const xrd = smem + lane * 16;                     // + (ks*4+nt)*1024

    #pragma unroll 1
    for (int hi = 0; hi < 2; ++hi) {
        const int h = wv + hi * 3;
        const unsigned short* const wqh = wq16 + (size_t)(h * 128 + lane) * 8;  // q:+(ks*36+ft)*512, k:+6144, v:+12288
        const float* const bcb = bias_cd + (size_t)(h * 1024 + lane) * 4;       // + (kt*4+qt)*256 floats

        // ---- fused q+k pass (x32): C^T = W @ x^T, 64 acc regs, shared xf ----
        u32x2 qb[2][4], kb[2][4];
        {
            f32x4 qa[2][4], ka[2][4];
            #pragma unroll
            for (int ft = 0; ft < 2; ++ft)
                #pragma unroll
                for (int nt = 0; nt < 4; ++nt) { qa[ft][nt] = (f32x4){0,0,0,0}; ka[ft][nt] = (f32x4){0,0,0,0}; }
            #pragma unroll 2
            for (int ks = 0; ks < 6; ++ks) {
                int4 wq[2], wk[2];
                #pragma unroll
                for (int ft = 0; ft < 2; ++ft) {
                    wq[ft] = *(const int4*)(wqh + (ks*36 + ft) * 512);
                    wk[ft] = *(const int4*)(wqh + (ks*36 + ft) * 512 + 6144);
                }
                #pragma unroll
                for (int nt = 0; nt < 4; ++nt) {
                    int4 xf = *(const int4*)(xrd + (ks*4 + nt) * 1024);
                    #pragma unroll
                    for (int ft = 0; ft < 2; ++ft) {
                        qa[ft][nt] = mfma32(wq[ft], xf, qa[ft][nt]);
                        ka[ft][nt] = mfma32(wk[ft], xf, ka[ft][nt]);
                    }
                }
            }
            // bias + pack straight into x16 A/B frags (C/D layout IS x16 layout)
            #pragma unroll
            for (int ft = 0; ft < 2; ++ft) {
                float4 tq = *(const float4*)(qkv_b + (h*2 + ft)*16 + quad*4);
                float4 tk = *(const float4*)(qkv_b + 192 + (h*2 + ft)*16 + quad*4);
                #pragma unroll
                for (int nt = 0; nt < 4; ++nt) {
                    qb[ft][nt] = (u32x2){ pack2(qa[ft][nt][0] + tq.x*SCALE, qa[ft][nt][1] + tq.y*SCALE),
                                          pack2(qa[ft][nt][2] + tq.z*SCALE, qa[ft][nt][3] + tq.w*SCALE) };
                    kb[ft][nt] = (u32x2){ pack2(ka[ft][nt][0] + tk.x, ka[ft][nt][1] + tk.y),
                                          pack2(ka[ft][nt][2] + tk.z, ka[ft][nt][3] + tk.w) };
                }
            }
        }

        // ---- S^T = k @ q^T + bias^T (x16), softmax over keys, P stays in regs ----
        float inv[4];
        u32x2 pf[4][4];                        // [kt][qt] -> PV B-frags, no LDS
        #pragma unroll
        for (int qt = 0; qt < 4; ++qt) {
            float sum = 0.f;
            #pragma unroll
            for (int kt = 0; kt < 4; ++kt) {
                f32x4 s = (f32x4){0,0,0,0};
                s = mfma16(kb[0][kt], qb[0][qt], s);
                s = mfma16(kb[1][kt], qb[1][qt], s);
                float4 bc = *(const float4*)(bcb + (kt*4 + qt) * 256);
                // logits are O(1); padded keys carry -1e30 -> exp underflows to 0
                float e0 = __expf(s[0] + bc.x);
                float e1 = __expf(s[1] + bc.y);
                float e2 = __expf(s[2] + bc.z);
                float e3 = __expf(s[3] + bc.w);
                sum += (e0 + e1) + (e2 + e3);
                pf[kt][qt] = (u32x2){ pack2(e0, e1), pack2(e2, e3) };
            }
            sum += __shfl_xor(sum, 16);
            sum += __shfl_xor(sum, 32);
            inv[qt] = 1.0f / sum;              // folded into O epilogue
        }

        // ---- v pass (x32): C = x @ Wv^T, 32 acc regs ----
        u32x2 vb[4][2];                        // [mt][nv] -> PV A-frags
        {
            f32x4 va[4][2];
            #pragma unroll
            for (int mt = 0; mt < 4; ++mt)
                #pragma unroll
                for (int nv = 0; nv < 2; ++nv) va[mt][nv] = (f32x4){0,0,0,0};
            #pragma unroll 2
            for (int ks = 0; ks < 6; ++ks) {
                int4 wvv[2];
                #pragma unroll
                for (int nv = 0; nv < 2; ++nv)
                    wvv[nv] = *(const int4*)(wqh + (ks*36 + nv) * 512 + 12288);
                #pragma unroll
                for (int mt = 0; mt < 4; ++mt) {
                    int4 xf = *(const int4*)(xrd + (ks*4 + mt) * 1024);
                    #pragma unroll
                    for (int nv = 0; nv < 2; ++nv)
                        va[mt][nv] = mfma32(xf, wvv[nv], va[mt][nv]);
                }
            }
            const float bv0 = qkv_b[384 + h*32 + l15];
            const float bv1 = qkv_b[384 + h*32 + 16 + l15];
            #pragma unroll
            for (int mt = 0; mt < 4; ++mt) {
                vb[mt][0] = (u32x2){ pack2(va[mt][0][0] + bv0, va[mt][0][1] + bv0),
                                     pack2(va[mt][0][2] + bv0, va[mt][0][3] + bv0) };
                vb[mt][1] = (u32x2){ pack2(va[mt][1][0] + bv1, va[mt][1][1] + bv1),
                                     pack2(va[mt][1][2] + bv1, va[mt][1][3] + bv1) };
            }
        }

        // ---- O^T = v^T @ P^T (x16) ----
        f32x4 oacc[2][4];                      // [nv][qt]
        #pragma unroll
        for (int nv = 0; nv < 2; ++nv)
            #pragma unroll
            for (int qt = 0; qt < 4; ++qt) oacc[nv][qt] = (f32x4){0,0,0,0};
        #pragma unroll
        for (int mt = 0; mt < 4; ++mt)
            #pragma unroll
            for (int nv = 0; nv < 2; ++nv)
                #pragma unroll
                for (int qt = 0; qt < 4; ++qt)
                    oacc[nv][qt] = mfma16(vb[mt][nv], pf[mt][qt], oacc[nv][qt]);

        // ---- epilogue: normalize, pack; C/D IS the x16-A frag for proj ----
        char* const og = (char*)outO + (size_t)widx * OUT_WIN_BYTES;
        #pragma unroll
        for (int nv = 0; nv < 2; ++nv) {
            #pragma unroll
            for (int qt = 0; qt < 4; ++qt) {
                u32x2 ow = (u32x2){ pack2(oacc[nv][qt][0] * inv[qt], oacc[nv][qt][1] * inv[qt]),
                                    pack2(oacc[nv][qt][2] * inv[qt], oacc[nv][qt][3] * inv[qt]) };
                *(u32x2*)(og + (size_t)(((h*2 + nv)*4 + qt) * 512) + lane * 8) = ow;
            }
        }
    }
}

// ---------- K2: out = O @ proj_w^T + proj_b (per window, x16 MFMAs) ----------
#define K2_LDS 24576

__global__ __launch_bounds__(384, 4) void proj_k(
    float* __restrict__ out,
    const unsigned short* __restrict__ wp16,
    const float* __restrict__ proj_b)
{
    extern __shared__ char smem[];
    const int tid  = threadIdx.x;
    const int lane = tid & 63;
    const int h    = tid >> 6;
    const int l15  = lane & 15;
    const int quad = lane >> 4;
    const int widx = blockIdx.x;

    char* const base = (char*)out + (size_t)widx * OUT_WIN_BYTES;
    #pragma unroll
    for (int i = 0; i < 4; ++i) {
        int c = tid + i * 384;                  // 1536 chunks of 16B = 24KB
        *(uint4*)(smem + (size_t)c * 16) = *(const uint4*)(base + (size_t)c * 16);
    }
    __syncthreads();                            // O staged; safe to overwrite slice

    char* const ard = smem + lane * 8;          // + (ks*4+mt)*512
    const char* const wpb = (const char*)wp16 + lane * 8;   // + (ks*12+ot)*512

    f32x4 acc[4][2];
    #pragma unroll
    for (int mt = 0; mt < 4; ++mt)
        #pragma unroll
        for (int j = 0; j < 2; ++j) acc[mt][j] = (f32x4){0, 0, 0, 0};
    #pragma unroll 3
    for (int ks = 0; ks < 12; ++ks) {
        u32x2 wb[2];
        #pragma unroll
        for (int j = 0; j < 2; ++j)
            wb[j] = *(const u32x2*)(wpb + (size_t)((ks*12 + h*2 + j) * 512));
        #pragma unroll
        for (int mt = 0; mt < 4; ++mt) {
            u32x2 oa = *(const u32x2*)(ard + (ks*4 + mt) * 512);
            #pragma unroll
            for (int j = 0; j < 2; ++j)
                acc[mt][j] = mfma16(oa, wb[j], acc[mt][j]);
        }
    }
    #pragma unroll
    for (int j = 0; j < 2; ++j) {
        const int o = (h*2 + j) * 16 + l15;
        const float pb = proj_b[o];
        #pragma unroll
        for (int mt = 0; mt < 4; ++mt) {
            const int t0 = mt * 16 + quad * 4;
            #pragma unroll
            for (int r = 0; r < 4; ++r) {
                const int t = t0 + r;
                if (t < NTOK)
                    out[((size_t)widx * NTOK + t) * DIM + o] = acc[mt][j][r] + pb;
            }
        }
    }
}

extern "C" void kernel_launch(void* const* d_in, const int* in_sizes, int n_in,
                              void* d_out, int out_size, void* d_ws, size_t ws_size,
                              hipStream_t stream) {
    const float* x          = (const float*)d_in[0];
    const float* qkv_w      = (const float*)d_in[1];
    const float* qkv_b      = (const float*)d_in[2];
    const float* proj_w     = (const float*)d_in[3];
    const float* proj_b     = (const float*)d_in[4];
    const float* bias_table = (const float*)d_in[5];
    const int*   rel_index  = (const int*)d_in[6];
    float* out = (float*)d_out;

    unsigned short* w16 = (unsigned short*)d_ws;
    float* bias_cd = (float*)((char*)d_ws + BIAS_BYTE);

    prep<<<96, 256, 0, stream>>>(qkv_w, proj_w, bias_table, rel_index, w16, bias_cd);

    (void)hipFuncSetAttribute((const void*)win_attn,
                              hipFuncAttributeMaxDynamicSharedMemorySize, K1_LDS);
    win_attn<<<4096, 192, K1_LDS, stream>>>(x, qkv_b, w16, bias_cd, out);

    (void)hipFuncSetAttribute((const void*)proj_k,
                              hipFuncAttributeMaxDynamicSharedMemorySize, K2_LDS);
    proj_k<<<4096, 384, K2_LDS, stream>>>(out, w16 + WPROJ_USH, proj_b);
}